// Round 3
// baseline (101.747 us; speedup 1.0000x reference)
//
#include <hip/hip_runtime.h>

#define NRAYS 2048
#define NS    128
#define G     128
#define FC    128
#define INC   390
#define APPC  27
#define TILE  16
#define MAXIT 64

// mlp_in layout:
//   [0,27) feats | [27,30) vd | [30,192) sin(feats*2^f) | [192,354) cos(feats*2^f)
//   [354,372) sin(vd*2^f) | [372,390) cos(vd*2^f)   (d-major, f-minor)

static __device__ __forceinline__ float tri_sample(const float* __restrict__ vol,
                                                   float gx, float gy, float gz) {
  int x0 = (int)gx; x0 = x0 < 0 ? 0 : (x0 > G - 2 ? G - 2 : x0);
  int y0 = (int)gy; y0 = y0 < 0 ? 0 : (y0 > G - 2 ? G - 2 : y0);
  int z0 = (int)gz; z0 = z0 < 0 ? 0 : (z0 > G - 2 ? G - 2 : z0);
  float fx = gx - (float)x0;
  float fy = gy - (float)y0;
  float fz = gz - (float)z0;
  const float* p = vol + ((z0 * G + y0) * G + x0);
  float v000 = p[0], v001 = p[1];
  float v010 = p[G], v011 = p[G + 1];
  const float* q = p + G * G;
  float v100 = q[0], v101 = q[1];
  float v110 = q[G], v111 = q[G + 1];
  float c00 = v000 + (v001 - v000) * fx;
  float c01 = v010 + (v011 - v010) * fx;
  float c10 = v100 + (v101 - v100) * fx;
  float c11 = v110 + (v111 - v110) * fx;
  float c0  = c00 + (c01 - c00) * fy;
  float c1  = c10 + (c11 - c10) * fy;
  return c0 + (c1 - c0) * fz;
}

// K0: bc[n] = b1[n] + sum_{k=192..353} W1[k][n], parallel (8 partials x 128 neurons).
__global__ __launch_bounds__(1024) void k_pre(const float* __restrict__ W1,
                                              const float* __restrict__ b1,
                                              float* __restrict__ bc) {
  __shared__ float s_sum[8][FC];
  const int n = threadIdx.x & 127, p = threadIdx.x >> 7;
  float v = 0.0f;
  for (int k = 192 + p; k < 354; k += 8) v += W1[k * FC + n];
  s_sum[p][n] = v;
  __syncthreads();
  if (threadIdx.x < FC) {
    float t = b1[n];
#pragma unroll
    for (int q = 0; q < 8; ++q) t += s_sum[q][n];
    bc[n] = t;
  }
}

// K1: everything, one block (256 threads) per ray.
__global__ __launch_bounds__(256) void k_fused(const float* __restrict__ rays_o,
                                               const float* __restrict__ rays_d,
                                               const float* __restrict__ dgrid,
                                               const float* __restrict__ agrid,
                                               const float* __restrict__ W1,
                                               const float* __restrict__ W2,
                                               const float* __restrict__ b3,
                                               const float* __restrict__ W3,
                                               const float* __restrict__ b1,
                                               const float* __restrict__ b2,
                                               const float* __restrict__ bc,
                                               float* __restrict__ out) {
  const int ray = blockIdx.x;
  const int tid = threadIdx.x;

  __shared__ float s_inT[INC][TILE];     // 24.4 KB; tail reused as h2 [128][20]
  __shared__ float s_hT[FC][20];         // 10 KB
  __shared__ float s_pp[2][NS];          // scan ping-pong / reductions / fast-path h
  __shared__ float s_wt[NS];
  __shared__ float s_W3[FC * 3];
  __shared__ float s_b1v[FC], s_b2v[FC], s_bcv[FC], s_b3v[4];
  __shared__ float s_pevd[36];
  __shared__ float s_dir[3], s_o[3];
  __shared__ int   s_items[MAXIT];
  __shared__ int   s_cnt[2];
  __shared__ float s_gx[TILE], s_gy[TILE], s_gz[TILE], s_jw[TILE];
  __shared__ int   s_vld[TILE];
  __shared__ float s_rgbw[TILE][3];
  __shared__ float s_out[3];

  // ---- stage small tensors + ray data (coalesced float4) ----
  if (tid < 96)       *(float4*)&s_W3[tid * 4]          = *(const float4*)&W3[tid * 4];
  else if (tid < 128) *(float4*)&s_b2v[(tid - 96) * 4]  = *(const float4*)&b2[(tid - 96) * 4];
  else if (tid < 160) *(float4*)&s_b1v[(tid - 128) * 4] = *(const float4*)&b1[(tid - 128) * 4];
  else if (tid < 192) *(float4*)&s_bcv[(tid - 160) * 4] = *(const float4*)&bc[(tid - 160) * 4];
  else if (tid < 195) s_b3v[tid - 192] = b3[tid - 192];
  else if (tid == 195) {
    float dxx = rays_d[ray * 3 + 0], dyy = rays_d[ray * 3 + 1], dzz = rays_d[ray * 3 + 2];
    float inv = rsqrtf(dxx * dxx + dyy * dyy + dzz * dzz);
    s_dir[0] = dxx * inv; s_dir[1] = dyy * inv; s_dir[2] = dzz * inv;
  } else if (tid == 196) {
    s_o[0] = rays_o[ray * 3 + 0]; s_o[1] = rays_o[ray * 3 + 1]; s_o[2] = rays_o[ray * 3 + 2];
  } else if (tid == 197) {
    s_out[0] = 0.0f; s_out[1] = 0.0f; s_out[2] = 0.0f;
  }
  __syncthreads();

  const float dx = s_dir[0], dy = s_dir[1], dz = s_dir[2];

  if (tid < 18) {  // PE(vd), shared by every item of this ray
    const int d = tid / 6, f = tid % 6;
    float ang = s_dir[d] * (float)(1 << f);
    float sn, cs; __sincosf(ang, &sn, &cs);
    s_pevd[tid] = sn; s_pevd[18 + tid] = cs;
  }

  // ---- alphas ----
  float alpha = 0.0f, w = 0.0f;
  bool inb = false;
  if (tid < NS) {
    const float t  = 2.0f + (4.0f / 127.0f) * (float)tid;
    const float px = (s_o[0] + dx * t) * (2.0f / 3.0f);
    const float py = (s_o[1] + dy * t) * (2.0f / 3.0f);
    const float pz = (s_o[2] + dz * t) * (2.0f / 3.0f);
    inb = (fabsf(px) <= 1.0f) && (fabsf(py) <= 1.0f) && (fabsf(pz) <= 1.0f);
    float sf = 0.0f;
    if (inb)
      sf = tri_sample(dgrid, (px + 1.0f) * 63.5f, (py + 1.0f) * 63.5f, (pz + 1.0f) * 63.5f);
    const float sigma = log1pf(__expf(sf - 10.0f));
    alpha = 1.0f - __expf(-sigma * 0.78125f);
    s_pp[0][tid] = 1.0f - alpha + 1e-10f;
  }
  __syncthreads();

  // ---- parallel product scan (Hillis-Steele, ping-pong) ----
  int src = 0;
#pragma unroll
  for (int off = 1; off < NS; off <<= 1) {
    float v = 0.0f;
    if (tid < NS) {
      v = s_pp[src][tid];
      if (tid >= off) v *= s_pp[src][tid - off];
      s_pp[src ^ 1][tid] = v;
    }
    __syncthreads();
    src ^= 1;
  }
  if (tid < NS) {
    const float T = (tid == 0) ? 1.0f : s_pp[src][tid - 1];
    w = alpha * T;
    s_wt[tid] = w;
  }
  __syncthreads();

  // ---- reductions (acc, w_oob) + deterministic ballot compaction ----
  unsigned long long m = 0ull;
  if (tid < NS) {
    s_pp[0][tid] = w;
    s_pp[1][tid] = inb ? 0.0f : w;
    m = __ballot(inb);
    if ((tid & 63) == 0) s_cnt[tid >> 6] = (int)__popcll(m);
  }
  __syncthreads();
#pragma unroll
  for (int off = 64; off > 0; off >>= 1) {
    if (tid < off) {
      s_pp[0][tid] += s_pp[0][tid + off];
      s_pp[1][tid] += s_pp[1][tid + off];
    }
    __syncthreads();
  }
  const float acc      = s_pp[0][0];
  const float woob_sum = s_pp[1][0];
  const int   n_in     = s_cnt[0] + s_cnt[1];
  if (tid < NS && inb) {
    const int rank = (int)__popcll(m & ((1ull << (tid & 63)) - 1));
    const int slot = ((tid < 64) ? 0 : s_cnt[0]) + rank;
    if (slot < MAXIT) s_items[slot] = tid;
  }
  __syncthreads();

  // ================= fast path: no in-bounds samples (≈75% of rays) =================
  if (n_in == 0) {
    if (tid < FC) {
      float a = s_bcv[tid];
      a = fmaf(dx, W1[27 * FC + tid], a);
      a = fmaf(dy, W1[28 * FC + tid], a);
      a = fmaf(dz, W1[29 * FC + tid], a);
#pragma unroll
      for (int k = 0; k < 36; ++k)
        a = fmaf(s_pevd[k], W1[(354 + k) * FC + tid], a);
      s_pp[0][tid] = fmaxf(a, 0.0f);
    }
    __syncthreads();
    {  // layer2 split across two halves of k
      const int nrn = tid & 127, h = tid >> 7;
      const int k0  = h * 64;
      float c = 0.0f;
#pragma unroll 8
      for (int kk = 0; kk < 64; ++kk) {
        const int k = k0 + kk;
        c = fmaf(s_pp[0][k], W2[k * FC + nrn], c);
      }
      s_hT[nrn][h] = c;
    }
    __syncthreads();
    if (tid < FC)
      s_pp[1][tid] = fmaxf(s_hT[tid][0] + s_hT[tid][1] + s_b2v[tid], 0.0f);
    __syncthreads();
    if (tid < 3) {
      float a3 = s_b3v[tid];
#pragma unroll 8
      for (int k = 0; k < FC; ++k)
        a3 = fmaf(s_pp[1][k], s_W3[k * 3 + tid], a3);
      const float rgb = 1.0f / (1.0f + __expf(-a3));
      const float val = woob_sum * rgb + (1.0f - acc);
      out[ray * 3 + tid] = fminf(fmaxf(val, 0.0f), 1.0f);
    }
    return;
  }

  // ================= mixed path: batched MLP, item 0 = virtual OOB sample =================
  const int n_items = n_in + 1;
  for (int base = 0; base < n_items; base += TILE) {
    const int nt = (n_items - base < TILE) ? (n_items - base) : TILE;

    if (tid < TILE) {
      const int j = tid, gi = base + j;
      float wj = 0.0f, gx = 0.0f, gy = 0.0f, gz = 0.0f;
      int vld = 0;
      if (j < nt) {
        if (gi == 0) {
          wj = woob_sum;  // feats stay 0 -> sin=0, cos=1 falls out of sincos(0)
        } else {
          const int s = s_items[gi - 1];
          wj = s_wt[s];
          const float t = 2.0f + (4.0f / 127.0f) * (float)s;
          gx = ((s_o[0] + dx * t) * (2.0f / 3.0f) + 1.0f) * 63.5f;
          gy = ((s_o[1] + dy * t) * (2.0f / 3.0f) + 1.0f) * 63.5f;
          gz = ((s_o[2] + dz * t) * (2.0f / 3.0f) + 1.0f) * 63.5f;
          vld = 1;
        }
      }
      s_jw[j] = wj; s_gx[j] = gx; s_gy[j] = gy; s_gz[j] = gz; s_vld[j] = vld;
    }
    __syncthreads();

    // feats rows (27 x 16)
    for (int a2 = tid; a2 < APPC * TILE; a2 += 256) {
      const int j = a2 & (TILE - 1), c = a2 >> 4;
      s_inT[c][j] = s_vld[j]
                        ? tri_sample(agrid + (size_t)c * G * G * G, s_gx[j], s_gy[j], s_gz[j])
                        : 0.0f;
    }
    // vd rows + PE(vd) rows (ray-constant, broadcast to all items)
    for (int a2 = tid; a2 < 3 * TILE; a2 += 256) {
      const int j = a2 & (TILE - 1), d = a2 >> 4;
      s_inT[27 + d][j] = s_dir[d];
    }
    for (int a2 = tid; a2 < 36 * TILE; a2 += 256) {
      const int j = a2 & (TILE - 1), idx = a2 >> 4;
      s_inT[354 + idx][j] = s_pevd[idx];
    }
    __syncthreads();

    // PE(feats) rows (162 x 16)
    for (int a2 = tid; a2 < 162 * TILE; a2 += 256) {
      const int j = a2 & (TILE - 1), idx = a2 >> 4;
      const int d = idx / 6, f = idx % 6;
      float ang = s_inT[d][j] * (float)(1 << f);
      float sn, cs; __sincosf(ang, &sn, &cs);
      s_inT[30 + idx][j]  = sn;
      s_inT[192 + idx][j] = cs;
    }
    __syncthreads();

    const int nrn = tid & 127;
    const int j0  = (tid >> 7) * 8;

    // layer 1
    float a1[8];
    {
      const float bb = s_b1v[nrn];
#pragma unroll
      for (int i = 0; i < 8; ++i) a1[i] = bb;
    }
#pragma unroll 4
    for (int k = 0; k < INC; ++k) {
      const float wv = W1[k * FC + nrn];
      const float4 v0 = *(const float4*)&s_inT[k][j0];
      const float4 v1 = *(const float4*)&s_inT[k][j0 + 4];
      a1[0] = fmaf(v0.x, wv, a1[0]); a1[1] = fmaf(v0.y, wv, a1[1]);
      a1[2] = fmaf(v0.z, wv, a1[2]); a1[3] = fmaf(v0.w, wv, a1[3]);
      a1[4] = fmaf(v1.x, wv, a1[4]); a1[5] = fmaf(v1.y, wv, a1[5]);
      a1[6] = fmaf(v1.z, wv, a1[6]); a1[7] = fmaf(v1.w, wv, a1[7]);
    }
#pragma unroll
    for (int i = 0; i < 8; ++i) s_hT[nrn][j0 + i] = fmaxf(a1[i], 0.0f);
    __syncthreads();

    // layer 2
    float a2v[8];
    {
      const float bb = s_b2v[nrn];
#pragma unroll
      for (int i = 0; i < 8; ++i) a2v[i] = bb;
    }
#pragma unroll 4
    for (int k = 0; k < FC; ++k) {
      const float wv = W2[k * FC + nrn];
      const float4 u0 = *(const float4*)&s_hT[k][j0];
      const float4 u1 = *(const float4*)&s_hT[k][j0 + 4];
      a2v[0] = fmaf(u0.x, wv, a2v[0]); a2v[1] = fmaf(u0.y, wv, a2v[1]);
      a2v[2] = fmaf(u0.z, wv, a2v[2]); a2v[3] = fmaf(u0.w, wv, a2v[3]);
      a2v[4] = fmaf(u1.x, wv, a2v[4]); a2v[5] = fmaf(u1.y, wv, a2v[5]);
      a2v[6] = fmaf(u1.z, wv, a2v[6]); a2v[7] = fmaf(u1.w, wv, a2v[7]);
    }
    float* s_h2 = &s_inT[0][0];  // reuse as [128][20]; layer-1 reads of s_inT are done
#pragma unroll
    for (int i = 0; i < 8; ++i) s_h2[nrn * 20 + j0 + i] = fmaxf(a2v[i], 0.0f);
    __syncthreads();

    // layer 3 + per-item rgb*w
    if (tid < 3 * TILE) {
      const int j = tid / 3, c = tid - j * 3;
      if (j < nt) {
        float a3 = s_b3v[c];
#pragma unroll 8
        for (int k = 0; k < FC; ++k)
          a3 = fmaf(s_h2[k * 20 + j], s_W3[k * 3 + c], a3);
        const float rgb = 1.0f / (1.0f + __expf(-a3));
        s_rgbw[j][c] = s_jw[j] * rgb;
      }
    }
    __syncthreads();
    if (tid < 3) {
      float v = s_out[tid];
      for (int j = 0; j < nt; ++j) v += s_rgbw[j][tid];
      s_out[tid] = v;
    }
    __syncthreads();
  }

  if (tid < 3) {
    const float val = s_out[tid] + (1.0f - acc);
    out[ray * 3 + tid] = fminf(fmaxf(val, 0.0f), 1.0f);
  }
}

extern "C" void kernel_launch(void* const* d_in, const int* in_sizes, int n_in,
                              void* d_out, int out_size, void* d_ws, size_t ws_size,
                              hipStream_t stream) {
  const float* rays_o = (const float*)d_in[0];
  const float* rays_d = (const float*)d_in[1];
  const float* dgrid  = (const float*)d_in[2];
  const float* agrid  = (const float*)d_in[3];
  const float* W1     = (const float*)d_in[4];
  const float* b1     = (const float*)d_in[5];
  const float* W2     = (const float*)d_in[6];
  const float* b2     = (const float*)d_in[7];
  const float* W3     = (const float*)d_in[8];
  const float* b3     = (const float*)d_in[9];
  float* out = (float*)d_out;

  float* bc = (float*)d_ws;  // 128 floats

  hipLaunchKernelGGL(k_pre, dim3(1), dim3(1024), 0, stream, W1, b1, bc);
  hipLaunchKernelGGL(k_fused, dim3(NRAYS), dim3(256), 0, stream,
                     rays_o, rays_d, dgrid, agrid, W1, W2, b3, W3, b1, b2, bc, out);
}